// Round 9
// baseline (253.523 us; speedup 1.0000x reference)
//
#include <hip/hip_runtime.h>
#include <hip/hip_bf16.h>

#define B_ 2
#define T_ 2048
#define E_ 1024
#define H_ 16
#define D_ 64
#define F_ 3072
#define M_ 4096        // B_*T_
#define VT_STRIDE 2080 // padded V^T row stride (breaks 4KB L1-set aliasing)
#define QSCALE 0.1803368801111f  // D^-0.5 * log2(e): softmax runs in exp2 domain
#define THR_LOG2 11.5f           // defer-max threshold (= 8 in ln domain)

typedef __attribute__((ext_vector_type(8))) short short8v;
typedef __attribute__((ext_vector_type(4))) float float4v;

#if __has_builtin(__builtin_amdgcn_exp2f)
#define EXP2(x) __builtin_amdgcn_exp2f(x)
#else
#define EXP2(x) exp2f(x)
#endif

#define AS1 const __attribute__((address_space(1))) void*
#define AS3 __attribute__((address_space(3))) void*

// packed fp32x2 -> bf16x2 (v_cvt_pk_bf16_f32, RNE)
__device__ __forceinline__ unsigned cvtpk(float lo, float hi) {
    union { __hip_bfloat162 h; unsigned u; } x;
    x.h = __float22bfloat162_rn(float2{lo, hi});
    return x.u;
}
__device__ __forceinline__ ushort f2bf(float f) { return (ushort)cvtpk(f, f); }

// ---- fp32 -> bf16 conversion, 4 elems per thread ----
__global__ void cvt_kernel(const float* __restrict__ in, ushort* __restrict__ out, int n4) {
    int i = blockIdx.x * blockDim.x + threadIdx.x;
    if (i >= n4) return;
    float4 v = ((const float4*)in)[i];
    uint2 o;
    o.x = cvtpk(v.x, v.y);
    o.y = cvtpk(v.z, v.w);
    ((uint2*)out)[i] = o;
}

// ---- GEMM: C[M][N] = A[M][K] * Bt[N][K]^T  (bf16, K mult of 64) ----
// m97-class structure: 128x128 tile, BK=64, global_load_lds(16B) staging,
// both-sides XOR swizzle. MODE 0: qkv epilogue (V^T stores vectorized as
// ushort4 — perm makes ri-consecutive t's contiguous). MODE 1: fp32 + bias.
template <int MODE>
__global__ __launch_bounds__(256) void gemm_bt(const ushort* __restrict__ A,
                                               const ushort* __restrict__ Bt,
                                               const float* __restrict__ bias,
                                               void* __restrict__ Cout,
                                               int Ndim, int K) {
    __shared__ __attribute__((aligned(16))) char lds[32768]; // A:[0,16K) B:[16K,32K)
    int t = threadIdx.x;
    int lane = t & 63;
    int w = t >> 6;
    int wr = w >> 1, wc = w & 1;
    int bm0 = blockIdx.x * 128, bn0 = blockIdx.y * 128;
    int mb = bm0 + wr * 64;
    int nb = bn0 + wc * 64;
    int r15 = lane & 15, g = lane >> 4;

    int srow = w * 8 + (lane >> 3);
    int schunk = (lane & 7) ^ (lane >> 3);
    const ushort* Asrc = A + (size_t)(bm0 + srow) * K + schunk * 8;
    const ushort* Bsrc = Bt + (size_t)(bn0 + srow) * K + schunk * 8;

    int rxor7 = r15 & 7;
    int abase = (wr * 64 + r15) * 128;
    int bbase = 16384 + (wc * 64 + r15) * 128;

    float4v acc[4][4] = {};
    for (int k0 = 0; k0 < K; k0 += 64) {
#pragma unroll
        for (int j = 0; j < 4; ++j) {
            __builtin_amdgcn_global_load_lds(
                (AS1)(Asrc + (size_t)(j * 32) * K + k0),
                (AS3)(lds + j * 4096 + w * 1024), 16, 0, 0);
            __builtin_amdgcn_global_load_lds(
                (AS1)(Bsrc + (size_t)(j * 32) * K + k0),
                (AS3)(lds + 16384 + j * 4096 + w * 1024), 16, 0, 0);
        }
        __syncthreads();

        short8v af[4][2], bf[4][2];
#pragma unroll
        for (int r = 0; r < 4; ++r)
#pragma unroll
            for (int h = 0; h < 2; ++h)
                af[r][h] = *(const short8v*)(lds + abase + r * 2048 +
                                             (((h * 4 + g) ^ rxor7) << 4));
#pragma unroll
        for (int c = 0; c < 4; ++c)
#pragma unroll
            for (int h = 0; h < 2; ++h)
                bf[c][h] = *(const short8v*)(lds + bbase + c * 2048 +
                                             (((h * 4 + g) ^ rxor7) << 4));
#pragma unroll
        for (int r = 0; r < 4; ++r)
#pragma unroll
            for (int c = 0; c < 4; ++c) {
                acc[r][c] = __builtin_amdgcn_mfma_f32_16x16x32_bf16(af[r][0], bf[c][0], acc[r][c], 0, 0, 0);
                acc[r][c] = __builtin_amdgcn_mfma_f32_16x16x32_bf16(af[r][1], bf[c][1], acc[r][c], 0, 0, 0);
            }
        __syncthreads();
    }

    if (MODE == 0) {
        ushort* qkv = (ushort*)Cout;
#pragma unroll
        for (int r = 0; r < 4; ++r)
#pragma unroll
            for (int c = 0; c < 4; ++c) {
                int n0 = nb + c * 16;          // block-uniform 1024-segment
                int which = n0 >> 10;          // 0:q 1:k 2:v
                int n = n0 + r15;
                int e = n & 1023;
                int h = e >> 6, d = e & 63;
                int m0 = mb + r * 16 + g * 4;
                int b = m0 >> 11, t0 = m0 & 2047;
                if (which == 2) {
                    // V^T vectorized: perm makes t0..t0+3 contiguous columns
                    int tt = t0 & 63;
                    int c64 = ((tt >> 2) & 3) * 16 + (tt >> 4) * 4 + (tt & 3);
                    size_t addr = (size_t)2 * M_ * E_ +
                                  ((size_t)(b * H_ + h) * D_ + d) * VT_STRIDE +
                                  ((t0 & ~63) | c64);
                    float bv = bias[n];
                    ushort4 o;
                    o.x = f2bf(acc[r][c][0] + bv);
                    o.y = f2bf(acc[r][c][1] + bv);
                    o.z = f2bf(acc[r][c][2] + bv);
                    o.w = f2bf(acc[r][c][3] + bv);
                    *(ushort4*)(qkv + addr) = o;
                } else {
                    float bv = bias[n];
                    float sc = (which == 0) ? QSCALE : 1.0f;
#pragma unroll
                    for (int ri = 0; ri < 4; ++ri) {
                        float v = (acc[r][c][ri] + bv) * sc;
                        size_t addr = (size_t)which * M_ * E_ +
                                      ((size_t)(b * H_ + h) * T_ + t0 + ri) * D_ + d;
                        qkv[addr] = f2bf(v);
                    }
                }
            }
    } else {
        float* out = (float*)Cout;
#pragma unroll
        for (int r = 0; r < 4; ++r)
#pragma unroll
            for (int c = 0; c < 4; ++c)
#pragma unroll
                for (int ri = 0; ri < 4; ++ri) {
                    int m = mb + r * 16 + g * 4 + ri;
                    int n = nb + c * 16 + r15;
                    out[(size_t)m * Ndim + n] = acc[r][c][ri] + bias[n];
                }
    }
}

// ---- flash attention: 1 block = (head, 128 q-rows); 8 waves (512 thr) ----
// Split-keys: super-tile = 128 keys in LDS; waves 0-3 take keys [0,64),
// waves 4-7 take [64,128), each with independent online softmax (wave w
// pairs with w+4 on the same 32 q-rows); exact flash-combine at the end via
// the freed staging LDS. Doubles waves/SIMD (2->4) at constant LDS traffic.
// K/V double-buffered via global_load_lds + counted vmcnt(4) + raw barriers.
__global__ __launch_bounds__(512, 4) void attn_kernel(const ushort* __restrict__ qkv,
                                                      ushort* __restrict__ Ob) {
    __shared__ __attribute__((aligned(16))) char lds[65536]; // 2 x (K 16K | V 16K)
    int tid = threadIdx.x;
    int lane = tid & 63;
    int w = tid >> 6;          // 0..7
    int gid = w >> 2;          // key-half group
    int wp = w & 3;            // pair id: wave wp and wp+4 share q-rows
    int bid = blockIdx.x;
    // XCD swizzle: give each XCD 4 whole heads so K/V (2MB) stays in its L2.
    int slot = bid >> 3;
    int bh = (bid & 7) * 4 + (slot >> 4);   // b*H + h
    int qt = slot & 15;
    int r15 = lane & 15, g = lane >> 4;
    int qb = qt * 128 + wp * 32;

    const ushort* Qh = qkv + (size_t)bh * T_ * D_;
    const ushort* Kh = qkv + (size_t)M_ * E_ + (size_t)bh * T_ * D_;
    const ushort* Vt = qkv + (size_t)2 * M_ * E_ + (size_t)bh * D_ * VT_STRIDE;

    const ushort* QrowA = Qh + (size_t)(qb + r15) * D_ + g * 8;
    short8v qfA0 = *(const short8v*)(QrowA);
    short8v qfA1 = *(const short8v*)(QrowA + 32);
    short8v qfB0 = *(const short8v*)(QrowA + 16 * D_);
    short8v qfB1 = *(const short8v*)(QrowA + 16 * D_ + 32);
    // anchor Q loads: drain them now so the staging vmcnt ledger stays exact
    asm volatile("" :: "v"(qfA0), "v"(qfA1), "v"(qfB0), "v"(qfB1));

    float4v oaccA[4] = {}, oaccB[4] = {};
    float mA = -1e30f, lA = 0.f;
    float mB = -1e30f, lB = 0.f;

    // ---- staging: K super-tile 128 rows x 128B (rows=keys); V 64 rows x 256B
    // (rows=d, 16 chunks). Both-sides swizzle: K chunk ^= row&7, V chunk ^= row&15.
    int srowK = tid >> 3;                       // 0..63
    int slcK = (tid & 7) ^ (srowK & 7);
    const ushort* Ksrc = Kh + (size_t)srowK * D_ + slcK * 8;
    int srowV = tid >> 4;                       // 0..31
    int slcV = (tid & 15) ^ (srowV & 15);
    const ushort* Vsrc = Vt + (size_t)srowV * VT_STRIDE + slcV * 8;

    auto stage = [&](int st, int base) {
        const ushort* kp = Ksrc + (size_t)st * 128 * D_;
        const ushort* vp = Vsrc + st * 128;
        __builtin_amdgcn_global_load_lds((AS1)kp, (AS3)(lds + base + tid * 16), 16, 0, 0);
        __builtin_amdgcn_global_load_lds((AS1)(kp + (size_t)64 * D_),
                                         (AS3)(lds + base + 8192 + tid * 16), 16, 0, 0);
        __builtin_amdgcn_global_load_lds((AS1)vp, (AS3)(lds + base + 16384 + tid * 16), 16, 0, 0);
        __builtin_amdgcn_global_load_lds((AS1)(vp + (size_t)32 * VT_STRIDE),
                                         (AS3)(lds + base + 24576 + tid * 16), 16, 0, 0);
    };

    // ---- frag read offsets ----
    int rxor = (r15 & 7) << 4;
    int rowb = r15 * 128;
    int kbg = gid * 8192;                       // this group's 64-key half
    int kc0 = (g << 4) ^ rxor;
    int kc1 = ((g + 4) << 4) ^ rxor;
    int vrow = r15 * 256;
    int vc0 = ((gid * 8 + 2 * g) ^ r15) << 4;
    int vc1 = ((gid * 8 + 2 * g + 1) ^ r15) << 4;

    auto softmax64 = [&](const float4v& s0, const float4v& s1, const float4v& s2,
                         const float4v& s3, float& m_run, float& l_run,
                         float4v* oacc, short8v& pf0, short8v& pf1) {
        float t0 = fmaxf(fmaxf(s0[0], s0[1]), fmaxf(s0[2], s0[3]));
        float t1 = fmaxf(fmaxf(s1[0], s1[1]), fmaxf(s1[2], s1[3]));
        float t2 = fmaxf(fmaxf(s2[0], s2[1]), fmaxf(s2[2], s2[3]));
        float t3 = fmaxf(fmaxf(s3[0], s3[1]), fmaxf(s3[2], s3[3]));
        float tmax = fmaxf(fmaxf(t0, t1), fmaxf(t2, t3));
        if (!__all(tmax - m_run <= THR_LOG2)) {   // rare: rescale path
            float tr = fmaxf(tmax, __shfl_xor(tmax, 16));
            tr = fmaxf(tr, __shfl_xor(tr, 32));
            float mnew = fmaxf(m_run, tr);
            float corr = EXP2(m_run - mnew);
            float c0 = __shfl(corr, g * 4 + 0);
            float c1 = __shfl(corr, g * 4 + 1);
            float c2 = __shfl(corr, g * 4 + 2);
            float c3 = __shfl(corr, g * 4 + 3);
#pragma unroll
            for (int c = 0; c < 4; ++c) {
                oacc[c][0] *= c0; oacc[c][1] *= c1;
                oacc[c][2] *= c2; oacc[c][3] *= c3;
            }
            l_run *= corr;
            m_run = mnew;
        }
        float p0 = EXP2(s0[0] - m_run), p1 = EXP2(s0[1] - m_run);
        float p2 = EXP2(s0[2] - m_run), p3 = EXP2(s0[3] - m_run);
        float p4 = EXP2(s1[0] - m_run), p5 = EXP2(s1[1] - m_run);
        float p6 = EXP2(s1[2] - m_run), p7 = EXP2(s1[3] - m_run);
        float p8 = EXP2(s2[0] - m_run), p9 = EXP2(s2[1] - m_run);
        float pa = EXP2(s2[2] - m_run), pb = EXP2(s2[3] - m_run);
        float pc = EXP2(s3[0] - m_run), pd = EXP2(s3[1] - m_run);
        float pe = EXP2(s3[2] - m_run), pg = EXP2(s3[3] - m_run);
        l_run += (((p0 + p1) + (p2 + p3)) + ((p4 + p5) + (p6 + p7))) +
                 (((p8 + p9) + (pa + pb)) + ((pc + pd) + (pe + pg)));
        union { short8v v; unsigned u[4]; } u0, u1;
        u0.u[0] = cvtpk(p0, p1); u0.u[1] = cvtpk(p2, p3);
        u0.u[2] = cvtpk(p4, p5); u0.u[3] = cvtpk(p6, p7);
        u1.u[0] = cvtpk(p8, p9); u1.u[1] = cvtpk(pa, pb);
        u1.u[2] = cvtpk(pc, pd); u1.u[3] = cvtpk(pe, pg);
        pf0 = u0.v; pf1 = u1.v;
    };

    auto compute = [&](int base) {
        const char* kb_ = lds + base + kbg;
        const char* vb_ = lds + base + 16384;
        short8v k0a = *(const short8v*)(kb_ + rowb + kc0);
        short8v k0b = *(const short8v*)(kb_ + rowb + kc1);
        short8v k1a = *(const short8v*)(kb_ + 2048 + rowb + kc0);
        short8v k1b = *(const short8v*)(kb_ + 2048 + rowb + kc1);
        short8v k2a = *(const short8v*)(kb_ + 4096 + rowb + kc0);
        short8v k2b = *(const short8v*)(kb_ + 4096 + rowb + kc1);
        short8v k3a = *(const short8v*)(kb_ + 6144 + rowb + kc0);
        short8v k3b = *(const short8v*)(kb_ + 6144 + rowb + kc1);

        float4v sA0 = {}, sA1 = {}, sA2 = {}, sA3 = {};
        float4v sB0 = {}, sB1 = {}, sB2 = {}, sB3 = {};
        __builtin_amdgcn_s_setprio(1);
        sA0 = __builtin_amdgcn_mfma_f32_16x16x32_bf16(k0a, qfA0, sA0, 0, 0, 0);
        sA0 = __builtin_amdgcn_mfma_f32_16x16x32_bf16(k0b, qfA1, sA0, 0, 0, 0);
        sA1 = __builtin_amdgcn_mfma_f32_16x16x32_bf16(k1a, qfA0, sA1, 0, 0, 0);
        sA1 = __builtin_amdgcn_mfma_f32_16x16x32_bf16(k1b, qfA1, sA1, 0, 0, 0);
        sA2 = __builtin_amdgcn_mfma_f32_16x16x32_bf16(k2a, qfA0, sA2, 0, 0, 0);
        sA2 = __builtin_amdgcn_mfma_f32_16x16x32_bf16(k2b, qfA1, sA2, 0, 0, 0);
        sA3 = __builtin_amdgcn_mfma_f32_16x16x32_bf16(k3a, qfA0, sA3, 0, 0, 0);
        sA3 = __builtin_amdgcn_mfma_f32_16x16x32_bf16(k3b, qfA1, sA3, 0, 0, 0);
        sB0 = __builtin_amdgcn_mfma_f32_16x16x32_bf16(k0a, qfB0, sB0, 0, 0, 0);
        sB0 = __builtin_amdgcn_mfma_f32_16x16x32_bf16(k0b, qfB1, sB0, 0, 0, 0);
        sB1 = __builtin_amdgcn_mfma_f32_16x16x32_bf16(k1a, qfB0, sB1, 0, 0, 0);
        sB1 = __builtin_amdgcn_mfma_f32_16x16x32_bf16(k1b, qfB1, sB1, 0, 0, 0);
        sB2 = __builtin_amdgcn_mfma_f32_16x16x32_bf16(k2a, qfB0, sB2, 0, 0, 0);
        sB2 = __builtin_amdgcn_mfma_f32_16x16x32_bf16(k2b, qfB1, sB2, 0, 0, 0);
        sB3 = __builtin_amdgcn_mfma_f32_16x16x32_bf16(k3a, qfB0, sB3, 0, 0, 0);
        sB3 = __builtin_amdgcn_mfma_f32_16x16x32_bf16(k3b, qfB1, sB3, 0, 0, 0);
        __builtin_amdgcn_s_setprio(0);

        // issue V reads now; LDS latency hides under the softmax VALU
        short8v v0a = *(const short8v*)(vb_ + vrow + vc0);
        short8v v0b = *(const short8v*)(vb_ + vrow + vc1);
        short8v v1a = *(const short8v*)(vb_ + 4096 + vrow + vc0);
        short8v v1b = *(const short8v*)(vb_ + 4096 + vrow + vc1);
        short8v v2a = *(const short8v*)(vb_ + 8192 + vrow + vc0);
        short8v v2b = *(const short8v*)(vb_ + 8192 + vrow + vc1);
        short8v v3a = *(const short8v*)(vb_ + 12288 + vrow + vc0);
        short8v v3b = *(const short8v*)(vb_ + 12288 + vrow + vc1);

        short8v pA0, pA1, pB0, pB1;
        softmax64(sA0, sA1, sA2, sA3, mA, lA, oaccA, pA0, pA1);
        softmax64(sB0, sB1, sB2, sB3, mB, lB, oaccB, pB0, pB1);

        __builtin_amdgcn_s_setprio(1);
        oaccA[0] = __builtin_amdgcn_mfma_f32_16x16x32_bf16(pA0, v0a, oaccA[0], 0, 0, 0);
        oaccA[0] = __builtin_amdgcn_mfma_f32_16x16x32_bf16(pA1, v0b, oaccA[0], 0, 0, 0);
        oaccB[0] = __builtin_amdgcn_mfma_f32_16x16x32_bf16(pB0, v0a, oaccB[0], 0, 0, 0);
        oaccB[0] = __builtin_amdgcn_mfma_f32_16x16x32_bf16(pB1, v0b, oaccB[0], 0, 0, 0);
        oaccA[1] = __builtin_amdgcn_mfma_f32_16x16x32_bf16(pA0, v1a, oaccA[1], 0, 0, 0);
        oaccA[1] = __builtin_amdgcn_mfma_f32_16x16x32_bf16(pA1, v1b, oaccA[1], 0, 0, 0);
        oaccB[1] = __builtin_amdgcn_mfma_f32_16x16x32_bf16(pB0, v1a, oaccB[1], 0, 0, 0);
        oaccB[1] = __builtin_amdgcn_mfma_f32_16x16x32_bf16(pB1, v1b, oaccB[1], 0, 0, 0);
        oaccA[2] = __builtin_amdgcn_mfma_f32_16x16x32_bf16(pA0, v2a, oaccA[2], 0, 0, 0);
        oaccA[2] = __builtin_amdgcn_mfma_f32_16x16x32_bf16(pA1, v2b, oaccA[2], 0, 0, 0);
        oaccB[2] = __builtin_amdgcn_mfma_f32_16x16x32_bf16(pB0, v2a, oaccB[2], 0, 0, 0);
        oaccB[2] = __builtin_amdgcn_mfma_f32_16x16x32_bf16(pB1, v2b, oaccB[2], 0, 0, 0);
        oaccA[3] = __builtin_amdgcn_mfma_f32_16x16x32_bf16(pA0, v3a, oaccA[3], 0, 0, 0);
        oaccA[3] = __builtin_amdgcn_mfma_f32_16x16x32_bf16(pA1, v3b, oaccA[3], 0, 0, 0);
        oaccB[3] = __builtin_amdgcn_mfma_f32_16x16x32_bf16(pB0, v3a, oaccB[3], 0, 0, 0);
        oaccB[3] = __builtin_amdgcn_mfma_f32_16x16x32_bf16(pB1, v3b, oaccB[3], 0, 0, 0);
        __builtin_amdgcn_s_setprio(0);
    };

    // ---- pipelined loop over 16 super-tiles: counted vmcnt(4), never 0 mid-loop
    stage(0, 0);
    for (int st = 0; st < T_ / 128; st += 2) {
        stage(st + 1, 32768);
        asm volatile("s_waitcnt vmcnt(4)" ::: "memory");   // buf0's 4 landed
        __builtin_amdgcn_s_barrier();
        compute(0);
        __builtin_amdgcn_s_barrier();
        if (st + 2 < T_ / 128) {
            stage(st + 2, 0);
            asm volatile("s_waitcnt vmcnt(4)" ::: "memory");
        } else {
            asm volatile("s_waitcnt vmcnt(0)" ::: "memory");
        }
        __builtin_amdgcn_s_barrier();
        compute(32768);
        __builtin_amdgcn_s_barrier();
    }

    // ---- split-keys merge: exact flash combine of the two key-halves ----
    lA += __shfl_xor(lA, 16); lA += __shfl_xor(lA, 32);
    lB += __shfl_xor(lB, 16); lB += __shfl_xor(lB, 32);
    __syncthreads();
    float* mf = (float*)lds;
    int reg = wp * 2176;   // per-pair region: 64 stats + 2x1024 O floats
    if (gid == 1) {
        if (lane < 16) {
            mf[reg + lane] = mA;      mf[reg + 16 + lane] = lA;
            mf[reg + 32 + lane] = mB; mf[reg + 48 + lane] = lB;
        }
#pragma unroll
        for (int c = 0; c < 4; ++c)
#pragma unroll
            for (int ri = 0; ri < 4; ++ri) {
                mf[reg + 64 + (g * 4 + ri) * 64 + c * 16 + r15] = oaccA[c][ri];
                mf[reg + 1088 + (g * 4 + ri) * 64 + c * 16 + r15] = oaccB[c][ri];
            }
    }
    __syncthreads();
    if (gid == 0) {
        int b = bh >> 4, h = bh & 15;
        {   // subtile A (rows qb..qb+15)
            float mh = mf[reg + r15], lh = mf[reg + 16 + r15];
            float mM = fmaxf(mA, mh);
            float ca = EXP2(mA - mM), cb = EXP2(mh - mM);
            float inv = 1.f / (ca * lA + cb * lh);
            float af = ca * inv, bfx = cb * inv;
            float a0 = __shfl(af, g * 4 + 0), b0 = __shfl(bfx, g * 4 + 0);
            float a1 = __shfl(af, g * 4 + 1), b1 = __shfl(bfx, g * 4 + 1);
            float a2 = __shfl(af, g * 4 + 2), b2 = __shfl(bfx, g * 4 + 2);
            float a3 = __shfl(af, g * 4 + 3), b3 = __shfl(bfx, g * 4 + 3);
#pragma unroll
            for (int c = 0; c < 4; ++c) {
                size_t base = ((size_t)b * T_ + qb + g * 4) * E_ + h * 64 + c * 16 + r15;
                int lb = reg + 64 + g * 4 * 64 + c * 16 + r15;
                Ob[base]          = f2bf(a0 * oaccA[c][0] + b0 * mf[lb]);
                Ob[base + E_]     = f2bf(a1 * oaccA[c][1] + b1 * mf[lb + 64]);
                Ob[base + 2 * E_] = f2bf(a2 * oaccA[c][2] + b2 * mf[lb + 128]);
                Ob[base + 3 * E_] = f2bf(a3 * oaccA[c][3] + b3 * mf[lb + 192]);
            }
        }
        {   // subtile B (rows qb+16..qb+31)
            float mh = mf[reg + 32 + r15], lh = mf[reg + 48 + r15];
            float mM = fmaxf(mB, mh);
            float ca = EXP2(mB - mM), cb = EXP2(mh - mM);
            float inv = 1.f / (ca * lB + cb * lh);
            float af = ca * inv, bfx = cb * inv;
            float a0 = __shfl(af, g * 4 + 0), b0 = __shfl(bfx, g * 4 + 0);
            float a1 = __shfl(af, g * 4 + 1), b1 = __shfl(bfx, g * 4 + 1);
            float a2 = __shfl(af, g * 4 + 2), b2 = __shfl(bfx, g * 4 + 2);
            float a3 = __shfl(af, g * 4 + 3), b3 = __shfl(bfx, g * 4 + 3);
#pragma unroll
            for (int c = 0; c < 4; ++c) {
                size_t base = ((size_t)b * T_ + qb + 16 + g * 4) * E_ + h * 64 + c * 16 + r15;
                int lb = reg + 1088 + g * 4 * 64 + c * 16 + r15;
                Ob[base]          = f2bf(a0 * oaccB[c][0] + b0 * mf[lb]);
                Ob[base + E_]     = f2bf(a1 * oaccB[c][1] + b1 * mf[lb + 64]);
                Ob[base + 2 * E_] = f2bf(a2 * oaccB[c][2] + b2 * mf[lb + 128]);
                Ob[base + 3 * E_] = f2bf(a3 * oaccB[c][3] + b3 * mf[lb + 192]);
            }
        }
    }
}

extern "C" void kernel_launch(void* const* d_in, const int* in_sizes, int n_in,
                              void* d_out, int out_size, void* d_ws, size_t ws_size,
                              hipStream_t stream) {
    const float* query = (const float*)d_in[0];
    const float* Wqkv  = (const float*)d_in[1];
    const float* bqkv  = (const float*)d_in[2];
    const float* Wo    = (const float*)d_in[3];
    const float* bo    = (const float*)d_in[4];
    float* out = (float*)d_out;

    // workspace (bf16 elems), ~41 MB total. Ob aliases Xb (Xb dead after GEMM1).
    ushort* Xb    = (ushort*)d_ws;                        // M_*E_ (8 MB)
    ushort* Wqkvb = Xb + (size_t)M_ * E_;                 // F_*E_ (6 MB)
    ushort* Wob   = Wqkvb + (size_t)F_ * E_;              // E_*E_ (2 MB)
    ushort* QKVb  = Wob + (size_t)E_ * E_;                // 2*M_*E_ + B*H*D*VT_STRIDE
    ushort* Ob    = Xb;                                   // alias: [B*T][E]

    cvt_kernel<<<(M_ * E_ / 4 + 255) / 256, 256, 0, stream>>>(query, Xb, M_ * E_ / 4);
    cvt_kernel<<<(F_ * E_ / 4 + 255) / 256, 256, 0, stream>>>(Wqkv, Wqkvb, F_ * E_ / 4);
    cvt_kernel<<<(E_ * E_ / 4 + 255) / 256, 256, 0, stream>>>(Wo, Wob, E_ * E_ / 4);

    gemm_bt<0><<<dim3(M_ / 128, F_ / 128), 256, 0, stream>>>(Xb, Wqkvb, bqkv, QKVb, F_, E_);
    attn_kernel<<<(B_ * H_) * (T_ / 128), 512, 0, stream>>>(QKVb, Ob);
    gemm_bt<1><<<dim3(M_ / 128, E_ / 128), 256, 0, stream>>>(Ob, Wob, bo, out, E_, E_);
}

// Round 10
// 193.496 us; speedup vs baseline: 1.3102x; 1.3102x over previous
//
#include <hip/hip_runtime.h>
#include <hip/hip_bf16.h>

#define B_ 2
#define T_ 2048
#define E_ 1024
#define H_ 16
#define D_ 64
#define F_ 3072
#define M_ 4096        // B_*T_
#define VT_STRIDE 2080 // padded V^T row stride (breaks 4KB L1-set aliasing)
#define QSCALE 0.1803368801111f  // D^-0.5 * log2(e): softmax runs in exp2 domain
#define THR_LOG2 11.5f           // defer-max threshold (= 8 in ln domain)

typedef __attribute__((ext_vector_type(8))) short short8v;
typedef __attribute__((ext_vector_type(4))) float float4v;

#if __has_builtin(__builtin_amdgcn_exp2f)
#define EXP2(x) __builtin_amdgcn_exp2f(x)
#else
#define EXP2(x) exp2f(x)
#endif

#define AS1 const __attribute__((address_space(1))) void*
#define AS3 __attribute__((address_space(3))) void*

// packed fp32x2 -> bf16x2 (v_cvt_pk_bf16_f32, RNE)
__device__ __forceinline__ unsigned cvtpk(float lo, float hi) {
    union { __hip_bfloat162 h; unsigned u; } x;
    x.h = __float22bfloat162_rn(float2{lo, hi});
    return x.u;
}
__device__ __forceinline__ ushort f2bf(float f) { return (ushort)cvtpk(f, f); }

// ---- fp32 -> bf16 conversion, 4 elems per thread ----
__global__ void cvt_kernel(const float* __restrict__ in, ushort* __restrict__ out, int n4) {
    int i = blockIdx.x * blockDim.x + threadIdx.x;
    if (i >= n4) return;
    float4 v = ((const float4*)in)[i];
    uint2 o;
    o.x = cvtpk(v.x, v.y);
    o.y = cvtpk(v.z, v.w);
    ((uint2*)out)[i] = o;
}

// ---- GEMM: C[M][N] = A[M][K] * Bt[N][K]^T  (bf16, K mult of 64) ----
// m97-class structure: 128x128 tile, BK=64, global_load_lds(16B) staging,
// both-sides XOR swizzle. MODE 0: qkv epilogue (V^T stores vectorized as
// ushort4 — perm makes ri-consecutive t's contiguous). MODE 1: fp32 + bias.
template <int MODE>
__global__ __launch_bounds__(256) void gemm_bt(const ushort* __restrict__ A,
                                               const ushort* __restrict__ Bt,
                                               const float* __restrict__ bias,
                                               void* __restrict__ Cout,
                                               int Ndim, int K) {
    __shared__ __attribute__((aligned(16))) char lds[32768]; // A:[0,16K) B:[16K,32K)
    int t = threadIdx.x;
    int lane = t & 63;
    int w = t >> 6;
    int wr = w >> 1, wc = w & 1;
    int bm0 = blockIdx.x * 128, bn0 = blockIdx.y * 128;
    int mb = bm0 + wr * 64;
    int nb = bn0 + wc * 64;
    int r15 = lane & 15, g = lane >> 4;

    int srow = w * 8 + (lane >> 3);
    int schunk = (lane & 7) ^ (lane >> 3);
    const ushort* Asrc = A + (size_t)(bm0 + srow) * K + schunk * 8;
    const ushort* Bsrc = Bt + (size_t)(bn0 + srow) * K + schunk * 8;

    int rxor7 = r15 & 7;
    int abase = (wr * 64 + r15) * 128;
    int bbase = 16384 + (wc * 64 + r15) * 128;

    float4v acc[4][4] = {};
    for (int k0 = 0; k0 < K; k0 += 64) {
#pragma unroll
        for (int j = 0; j < 4; ++j) {
            __builtin_amdgcn_global_load_lds(
                (AS1)(Asrc + (size_t)(j * 32) * K + k0),
                (AS3)(lds + j * 4096 + w * 1024), 16, 0, 0);
            __builtin_amdgcn_global_load_lds(
                (AS1)(Bsrc + (size_t)(j * 32) * K + k0),
                (AS3)(lds + 16384 + j * 4096 + w * 1024), 16, 0, 0);
        }
        __syncthreads();

        short8v af[4][2], bf[4][2];
#pragma unroll
        for (int r = 0; r < 4; ++r)
#pragma unroll
            for (int h = 0; h < 2; ++h)
                af[r][h] = *(const short8v*)(lds + abase + r * 2048 +
                                             (((h * 4 + g) ^ rxor7) << 4));
#pragma unroll
        for (int c = 0; c < 4; ++c)
#pragma unroll
            for (int h = 0; h < 2; ++h)
                bf[c][h] = *(const short8v*)(lds + bbase + c * 2048 +
                                             (((h * 4 + g) ^ rxor7) << 4));
#pragma unroll
        for (int r = 0; r < 4; ++r)
#pragma unroll
            for (int c = 0; c < 4; ++c) {
                acc[r][c] = __builtin_amdgcn_mfma_f32_16x16x32_bf16(af[r][0], bf[c][0], acc[r][c], 0, 0, 0);
                acc[r][c] = __builtin_amdgcn_mfma_f32_16x16x32_bf16(af[r][1], bf[c][1], acc[r][c], 0, 0, 0);
            }
        __syncthreads();
    }

    if (MODE == 0) {
        ushort* qkv = (ushort*)Cout;
#pragma unroll
        for (int r = 0; r < 4; ++r)
#pragma unroll
            for (int c = 0; c < 4; ++c) {
                int n0 = nb + c * 16;          // block-uniform 1024-segment
                int which = n0 >> 10;          // 0:q 1:k 2:v
                int n = n0 + r15;
                int e = n & 1023;
                int h = e >> 6, d = e & 63;
                int m0 = mb + r * 16 + g * 4;
                int b = m0 >> 11, t0 = m0 & 2047;
                if (which == 2) {
                    // V^T vectorized: perm makes t0..t0+3 contiguous columns
                    int tt = t0 & 63;
                    int c64 = ((tt >> 2) & 3) * 16 + (tt >> 4) * 4 + (tt & 3);
                    size_t addr = (size_t)2 * M_ * E_ +
                                  ((size_t)(b * H_ + h) * D_ + d) * VT_STRIDE +
                                  ((t0 & ~63) | c64);
                    float bv = bias[n];
                    ushort4 o;
                    o.x = f2bf(acc[r][c][0] + bv);
                    o.y = f2bf(acc[r][c][1] + bv);
                    o.z = f2bf(acc[r][c][2] + bv);
                    o.w = f2bf(acc[r][c][3] + bv);
                    *(ushort4*)(qkv + addr) = o;
                } else {
                    float bv = bias[n];
                    float sc = (which == 0) ? QSCALE : 1.0f;
#pragma unroll
                    for (int ri = 0; ri < 4; ++ri) {
                        float v = (acc[r][c][ri] + bv) * sc;
                        size_t addr = (size_t)which * M_ * E_ +
                                      ((size_t)(b * H_ + h) * T_ + t0 + ri) * D_ + d;
                        qkv[addr] = f2bf(v);
                    }
                }
            }
    } else {
        float* out = (float*)Cout;
#pragma unroll
        for (int r = 0; r < 4; ++r)
#pragma unroll
            for (int c = 0; c < 4; ++c)
#pragma unroll
                for (int ri = 0; ri < 4; ++ri) {
                    int m = mb + r * 16 + g * 4 + ri;
                    int n = nb + c * 16 + r15;
                    out[(size_t)m * Ndim + n] = acc[r][c][ri] + bias[n];
                }
    }
}

// ---- flash attention: 1 block = (head, 128 q-rows); 8 waves (512 thr) ----
// Split-keys: super-tile = 128 keys in LDS; waves 0-3 take keys [0,64),
// waves 4-7 take [64,128), each with independent online softmax (wave w
// pairs with w+4 on the same 32 q-rows); exact flash-combine at the end via
// the freed staging LDS. Doubles waves/SIMD (2->4) at constant LDS traffic.
// K/V double-buffered via global_load_lds + counted vmcnt(4) + raw barriers.
// launch_bounds(512,2): R9's (512,4) was taken as 4 blocks/CU -> 64-VGPR cap
// -> spill storm (FETCH+WRITE 375MB). (512,2) caps at >=128 VGPR; working
// set ~100 fits; residency (2 blocks/CU = 4 waves/SIMD) comes from LDS.
__global__ __launch_bounds__(512, 2) void attn_kernel(const ushort* __restrict__ qkv,
                                                      ushort* __restrict__ Ob) {
    __shared__ __attribute__((aligned(16))) char lds[65536]; // 2 x (K 16K | V 16K)
    int tid = threadIdx.x;
    int lane = tid & 63;
    int w = tid >> 6;          // 0..7
    int gid = w >> 2;          // key-half group
    int wp = w & 3;            // pair id: wave wp and wp+4 share q-rows
    int bid = blockIdx.x;
    // XCD swizzle: give each XCD 4 whole heads so K/V (2MB) stays in its L2.
    int slot = bid >> 3;
    int bh = (bid & 7) * 4 + (slot >> 4);   // b*H + h
    int qt = slot & 15;
    int r15 = lane & 15, g = lane >> 4;
    int qb = qt * 128 + wp * 32;

    const ushort* Qh = qkv + (size_t)bh * T_ * D_;
    const ushort* Kh = qkv + (size_t)M_ * E_ + (size_t)bh * T_ * D_;
    const ushort* Vt = qkv + (size_t)2 * M_ * E_ + (size_t)bh * D_ * VT_STRIDE;

    const ushort* QrowA = Qh + (size_t)(qb + r15) * D_ + g * 8;
    short8v qfA0 = *(const short8v*)(QrowA);
    short8v qfA1 = *(const short8v*)(QrowA + 32);
    short8v qfB0 = *(const short8v*)(QrowA + 16 * D_);
    short8v qfB1 = *(const short8v*)(QrowA + 16 * D_ + 32);
    // anchor Q loads: drain them now so the staging vmcnt ledger stays exact
    asm volatile("" :: "v"(qfA0), "v"(qfA1), "v"(qfB0), "v"(qfB1));

    float4v oaccA[4] = {}, oaccB[4] = {};
    float mA = -1e30f, lA = 0.f;
    float mB = -1e30f, lB = 0.f;

    // ---- staging: K super-tile 128 rows x 128B (rows=keys); V 64 rows x 256B
    // (rows=d, 16 chunks). Both-sides swizzle: K chunk ^= row&7, V chunk ^= row&15.
    int srowK = tid >> 3;                       // 0..63
    int slcK = (tid & 7) ^ (srowK & 7);
    const ushort* Ksrc = Kh + (size_t)srowK * D_ + slcK * 8;
    int srowV = tid >> 4;                       // 0..31
    int slcV = (tid & 15) ^ (srowV & 15);
    const ushort* Vsrc = Vt + (size_t)srowV * VT_STRIDE + slcV * 8;

    auto stage = [&](int st, int base) {
        const ushort* kp = Ksrc + (size_t)st * 128 * D_;
        const ushort* vp = Vsrc + st * 128;
        __builtin_amdgcn_global_load_lds((AS1)kp, (AS3)(lds + base + tid * 16), 16, 0, 0);
        __builtin_amdgcn_global_load_lds((AS1)(kp + (size_t)64 * D_),
                                         (AS3)(lds + base + 8192 + tid * 16), 16, 0, 0);
        __builtin_amdgcn_global_load_lds((AS1)vp, (AS3)(lds + base + 16384 + tid * 16), 16, 0, 0);
        __builtin_amdgcn_global_load_lds((AS1)(vp + (size_t)32 * VT_STRIDE),
                                         (AS3)(lds + base + 24576 + tid * 16), 16, 0, 0);
    };

    // ---- frag read offsets ----
    int rxor = (r15 & 7) << 4;
    int rowb = r15 * 128;
    int kbg = gid * 8192;                       // this group's 64-key half
    int kc0 = (g << 4) ^ rxor;
    int kc1 = ((g + 4) << 4) ^ rxor;
    int vrow = r15 * 256;
    int vc0 = ((gid * 8 + 2 * g) ^ r15) << 4;
    int vc1 = ((gid * 8 + 2 * g + 1) ^ r15) << 4;

    auto softmax64 = [&](const float4v& s0, const float4v& s1, const float4v& s2,
                         const float4v& s3, float& m_run, float& l_run,
                         float4v* oacc, short8v& pf0, short8v& pf1) {
        float t0 = fmaxf(fmaxf(s0[0], s0[1]), fmaxf(s0[2], s0[3]));
        float t1 = fmaxf(fmaxf(s1[0], s1[1]), fmaxf(s1[2], s1[3]));
        float t2 = fmaxf(fmaxf(s2[0], s2[1]), fmaxf(s2[2], s2[3]));
        float t3 = fmaxf(fmaxf(s3[0], s3[1]), fmaxf(s3[2], s3[3]));
        float tmax = fmaxf(fmaxf(t0, t1), fmaxf(t2, t3));
        if (!__all(tmax - m_run <= THR_LOG2)) {   // rare: rescale path
            float tr = fmaxf(tmax, __shfl_xor(tmax, 16));
            tr = fmaxf(tr, __shfl_xor(tr, 32));
            float mnew = fmaxf(m_run, tr);
            float corr = EXP2(m_run - mnew);
            float c0 = __shfl(corr, g * 4 + 0);
            float c1 = __shfl(corr, g * 4 + 1);
            float c2 = __shfl(corr, g * 4 + 2);
            float c3 = __shfl(corr, g * 4 + 3);
#pragma unroll
            for (int c = 0; c < 4; ++c) {
                oacc[c][0] *= c0; oacc[c][1] *= c1;
                oacc[c][2] *= c2; oacc[c][3] *= c3;
            }
            l_run *= corr;
            m_run = mnew;
        }
        float p0 = EXP2(s0[0] - m_run), p1 = EXP2(s0[1] - m_run);
        float p2 = EXP2(s0[2] - m_run), p3 = EXP2(s0[3] - m_run);
        float p4 = EXP2(s1[0] - m_run), p5 = EXP2(s1[1] - m_run);
        float p6 = EXP2(s1[2] - m_run), p7 = EXP2(s1[3] - m_run);
        float p8 = EXP2(s2[0] - m_run), p9 = EXP2(s2[1] - m_run);
        float pa = EXP2(s2[2] - m_run), pb = EXP2(s2[3] - m_run);
        float pc = EXP2(s3[0] - m_run), pd = EXP2(s3[1] - m_run);
        float pe = EXP2(s3[2] - m_run), pg = EXP2(s3[3] - m_run);
        l_run += (((p0 + p1) + (p2 + p3)) + ((p4 + p5) + (p6 + p7))) +
                 (((p8 + p9) + (pa + pb)) + ((pc + pd) + (pe + pg)));
        union { short8v v; unsigned u[4]; } u0, u1;
        u0.u[0] = cvtpk(p0, p1); u0.u[1] = cvtpk(p2, p3);
        u0.u[2] = cvtpk(p4, p5); u0.u[3] = cvtpk(p6, p7);
        u1.u[0] = cvtpk(p8, p9); u1.u[1] = cvtpk(pa, pb);
        u1.u[2] = cvtpk(pc, pd); u1.u[3] = cvtpk(pe, pg);
        pf0 = u0.v; pf1 = u1.v;
    };

    auto compute = [&](int base) {
        const char* kb_ = lds + base + kbg;
        const char* vb_ = lds + base + 16384;
        short8v k0a = *(const short8v*)(kb_ + rowb + kc0);
        short8v k0b = *(const short8v*)(kb_ + rowb + kc1);
        short8v k1a = *(const short8v*)(kb_ + 2048 + rowb + kc0);
        short8v k1b = *(const short8v*)(kb_ + 2048 + rowb + kc1);
        short8v k2a = *(const short8v*)(kb_ + 4096 + rowb + kc0);
        short8v k2b = *(const short8v*)(kb_ + 4096 + rowb + kc1);
        short8v k3a = *(const short8v*)(kb_ + 6144 + rowb + kc0);
        short8v k3b = *(const short8v*)(kb_ + 6144 + rowb + kc1);

        float4v sA0 = {}, sA1 = {}, sA2 = {}, sA3 = {};
        float4v sB0 = {}, sB1 = {}, sB2 = {}, sB3 = {};
        __builtin_amdgcn_s_setprio(1);
        sA0 = __builtin_amdgcn_mfma_f32_16x16x32_bf16(k0a, qfA0, sA0, 0, 0, 0);
        sA0 = __builtin_amdgcn_mfma_f32_16x16x32_bf16(k0b, qfA1, sA0, 0, 0, 0);
        sA1 = __builtin_amdgcn_mfma_f32_16x16x32_bf16(k1a, qfA0, sA1, 0, 0, 0);
        sA1 = __builtin_amdgcn_mfma_f32_16x16x32_bf16(k1b, qfA1, sA1, 0, 0, 0);
        sA2 = __builtin_amdgcn_mfma_f32_16x16x32_bf16(k2a, qfA0, sA2, 0, 0, 0);
        sA2 = __builtin_amdgcn_mfma_f32_16x16x32_bf16(k2b, qfA1, sA2, 0, 0, 0);
        sA3 = __builtin_amdgcn_mfma_f32_16x16x32_bf16(k3a, qfA0, sA3, 0, 0, 0);
        sA3 = __builtin_amdgcn_mfma_f32_16x16x32_bf16(k3b, qfA1, sA3, 0, 0, 0);
        sB0 = __builtin_amdgcn_mfma_f32_16x16x32_bf16(k0a, qfB0, sB0, 0, 0, 0);
        sB0 = __builtin_amdgcn_mfma_f32_16x16x32_bf16(k0b, qfB1, sB0, 0, 0, 0);
        sB1 = __builtin_amdgcn_mfma_f32_16x16x32_bf16(k1a, qfB0, sB1, 0, 0, 0);
        sB1 = __builtin_amdgcn_mfma_f32_16x16x32_bf16(k1b, qfB1, sB1, 0, 0, 0);
        sB2 = __builtin_amdgcn_mfma_f32_16x16x32_bf16(k2a, qfB0, sB2, 0, 0, 0);
        sB2 = __builtin_amdgcn_mfma_f32_16x16x32_bf16(k2b, qfB1, sB2, 0, 0, 0);
        sB3 = __builtin_amdgcn_mfma_f32_16x16x32_bf16(k3a, qfB0, sB3, 0, 0, 0);
        sB3 = __builtin_amdgcn_mfma_f32_16x16x32_bf16(k3b, qfB1, sB3, 0, 0, 0);
        __builtin_amdgcn_s_setprio(0);

        // issue V reads now; LDS latency hides under the softmax VALU
        short8v v0a = *(const short8v*)(vb_ + vrow + vc0);
        short8v v0b = *(const short8v*)(vb_ + vrow + vc1);
        short8v v1a = *(const short8v*)(vb_ + 4096 + vrow + vc0);
        short8v v1b = *(const short8v*)(vb_ + 4096 + vrow + vc1);
        short8v v2a = *(const short8v*)(vb_ + 8192 + vrow + vc0);
        short8v v2b = *(const short8v*)(vb_ + 8192 + vrow + vc1);
        short8v v3a = *(const short8v*)(vb_ + 12288 + vrow + vc0);
        short8v v3b = *(const short8v*)(vb_ + 12288 + vrow + vc1);

        short8v pA0, pA1, pB0, pB1;
        softmax64(sA0, sA1, sA2, sA3, mA, lA, oaccA, pA0, pA1);
        softmax64(sB0, sB1, sB2, sB3, mB, lB, oaccB, pB0, pB1);

        __builtin_amdgcn_s_setprio(1);
        oaccA[0] = __builtin_amdgcn_mfma_f32_16x16x32_bf16(pA0, v0a, oaccA[0], 0, 0, 0);
        oaccA[0] = __builtin_amdgcn_mfma_f32_16x16x32_bf16(pA1, v0b, oaccA[0], 0, 0, 0);
        oaccB[0] = __builtin_amdgcn_mfma_f32_16x16x32_bf16(pB0, v0a, oaccB[0], 0, 0, 0);
        oaccB[0] = __builtin_amdgcn_mfma_f32_16x16x32_bf16(pB1, v0b, oaccB[0], 0, 0, 0);
        oaccA[1] = __builtin_amdgcn_mfma_f32_16x16x32_bf16(pA0, v1a, oaccA[1], 0, 0, 0);
        oaccA[1] = __builtin_amdgcn_mfma_f32_16x16x32_bf16(pA1, v1b, oaccA[1], 0, 0, 0);
        oaccB[1] = __builtin_amdgcn_mfma_f32_16x16x32_bf16(pB0, v1a, oaccB[1], 0, 0, 0);
        oaccB[1] = __builtin_amdgcn_mfma_f32_16x16x32_bf16(pB1, v1b, oaccB[1], 0, 0, 0);
        oaccA[2] = __builtin_amdgcn_mfma_f32_16x16x32_bf16(pA0, v2a, oaccA[2], 0, 0, 0);
        oaccA[2] = __builtin_amdgcn_mfma_f32_16x16x32_bf16(pA1, v2b, oaccA[2], 0, 0, 0);
        oaccB[2] = __builtin_amdgcn_mfma_f32_16x16x32_bf16(pB0, v2a, oaccB[2], 0, 0, 0);
        oaccB[2] = __builtin_amdgcn_mfma_f32_16x16x32_bf16(pB1, v2b, oaccB[2], 0, 0, 0);
        oaccA[3] = __builtin_amdgcn_mfma_f32_16x16x32_bf16(pA0, v3a, oaccA[3], 0, 0, 0);
        oaccA[3] = __builtin_amdgcn_mfma_f32_16x16x32_bf16(pA1, v3b, oaccA[3], 0, 0, 0);
        oaccB[3] = __builtin_amdgcn_mfma_f32_16x16x32_bf16(pB0, v3a, oaccB[3], 0, 0, 0);
        oaccB[3] = __builtin_amdgcn_mfma_f32_16x16x32_bf16(pB1, v3b, oaccB[3], 0, 0, 0);
        __builtin_amdgcn_s_setprio(0);
    };

    // ---- pipelined loop over 16 super-tiles: counted vmcnt(4), never 0 mid-loop
    stage(0, 0);
    for (int st = 0; st < T_ / 128; st += 2) {
        stage(st + 1, 32768);
        asm volatile("s_waitcnt vmcnt(4)" ::: "memory");   // buf0's 4 landed
        __builtin_amdgcn_s_barrier();
        compute(0);
        __builtin_amdgcn_s_barrier();
        if (st + 2 < T_ / 128) {
            stage(st + 2, 0);
            asm volatile("s_waitcnt vmcnt(4)" ::: "memory");
        } else {
            asm volatile("s_waitcnt vmcnt(0)" ::: "memory");
        }
        __builtin_amdgcn_s_barrier();
        compute(32768);
        __builtin_amdgcn_s_barrier();
    }

    // ---- split-keys merge: exact flash combine of the two key-halves ----
    lA += __shfl_xor(lA, 16); lA += __shfl_xor(lA, 32);
    lB += __shfl_xor(lB, 16); lB += __shfl_xor(lB, 32);
    __syncthreads();
    float* mf = (float*)lds;
    int reg = wp * 2176;   // per-pair region: 64 stats + 2x1024 O floats
    if (gid == 1) {
        if (lane < 16) {
            mf[reg + lane] = mA;      mf[reg + 16 + lane] = lA;
            mf[reg + 32 + lane] = mB; mf[reg + 48 + lane] = lB;
        }
#pragma unroll
        for (int c = 0; c < 4; ++c)
#pragma unroll
            for (int ri = 0; ri < 4; ++ri) {
                mf[reg + 64 + (g * 4 + ri) * 64 + c * 16 + r15] = oaccA[c][ri];
                mf[reg + 1088 + (g * 4 + ri) * 64 + c * 16 + r15] = oaccB[c][ri];
            }
    }
    __syncthreads();
    if (gid == 0) {
        int b = bh >> 4, h = bh & 15;
        {   // subtile A (rows qb..qb+15)
            float mh = mf[reg + r15], lh = mf[reg + 16 + r15];
            float mM = fmaxf(mA, mh);
            float ca = EXP2(mA - mM), cb = EXP2(mh - mM);
            float inv = 1.f / (ca * lA + cb * lh);
            float af = ca * inv, bfx = cb * inv;
            float a0 = __shfl(af, g * 4 + 0), b0 = __shfl(bfx, g * 4 + 0);
            float a1 = __shfl(af, g * 4 + 1), b1 = __shfl(bfx, g * 4 + 1);
            float a2 = __shfl(af, g * 4 + 2), b2 = __shfl(bfx, g * 4 + 2);
            float a3 = __shfl(af, g * 4 + 3), b3 = __shfl(bfx, g * 4 + 3);
#pragma unroll
            for (int c = 0; c < 4; ++c) {
                size_t base = ((size_t)b * T_ + qb + g * 4) * E_ + h * 64 + c * 16 + r15;
                int lb = reg + 64 + g * 4 * 64 + c * 16 + r15;
                Ob[base]          = f2bf(a0 * oaccA[c][0] + b0 * mf[lb]);
                Ob[base + E_]     = f2bf(a1 * oaccA[c][1] + b1 * mf[lb + 64]);
                Ob[base + 2 * E_] = f2bf(a2 * oaccA[c][2] + b2 * mf[lb + 128]);
                Ob[base + 3 * E_] = f2bf(a3 * oaccA[c][3] + b3 * mf[lb + 192]);
            }
        }
        {   // subtile B (rows qb+16..qb+31)
            float mh = mf[reg + 32 + r15], lh = mf[reg + 48 + r15];
            float mM = fmaxf(mB, mh);
            float ca = EXP2(mB - mM), cb = EXP2(mh - mM);
            float inv = 1.f / (ca * lB + cb * lh);
            float af = ca * inv, bfx = cb * inv;
            float a0 = __shfl(af, g * 4 + 0), b0 = __shfl(bfx, g * 4 + 0);
            float a1 = __shfl(af, g * 4 + 1), b1 = __shfl(bfx, g * 4 + 1);
            float a2 = __shfl(af, g * 4 + 2), b2 = __shfl(bfx, g * 4 + 2);
            float a3 = __shfl(af, g * 4 + 3), b3 = __shfl(bfx, g * 4 + 3);
#pragma unroll
            for (int c = 0; c < 4; ++c) {
                size_t base = ((size_t)b * T_ + qb + 16 + g * 4) * E_ + h * 64 + c * 16 + r15;
                int lb = reg + 1088 + g * 4 * 64 + c * 16 + r15;
                Ob[base]          = f2bf(a0 * oaccB[c][0] + b0 * mf[lb]);
                Ob[base + E_]     = f2bf(a1 * oaccB[c][1] + b1 * mf[lb + 64]);
                Ob[base + 2 * E_] = f2bf(a2 * oaccB[c][2] + b2 * mf[lb + 128]);
                Ob[base + 3 * E_] = f2bf(a3 * oaccB[c][3] + b3 * mf[lb + 192]);
            }
        }
    }
}

extern "C" void kernel_launch(void* const* d_in, const int* in_sizes, int n_in,
                              void* d_out, int out_size, void* d_ws, size_t ws_size,
                              hipStream_t stream) {
    const float* query = (const float*)d_in[0];
    const float* Wqkv  = (const float*)d_in[1];
    const float* bqkv  = (const float*)d_in[2];
    const float* Wo    = (const float*)d_in[3];
    const float* bo    = (const float*)d_in[4];
    float* out = (float*)d_out;

    // workspace (bf16 elems), ~41 MB total. Ob aliases Xb (Xb dead after GEMM1).
    ushort* Xb    = (ushort*)d_ws;                        // M_*E_ (8 MB)
    ushort* Wqkvb = Xb + (size_t)M_ * E_;                 // F_*E_ (6 MB)
    ushort* Wob   = Wqkvb + (size_t)F_ * E_;              // E_*E_ (2 MB)
    ushort* QKVb  = Wob + (size_t)E_ * E_;                // 2*M_*E_ + B*H*D*VT_STRIDE
    ushort* Ob    = Xb;                                   // alias: [B*T][E]

    cvt_kernel<<<(M_ * E_ / 4 + 255) / 256, 256, 0, stream>>>(query, Xb, M_ * E_ / 4);
    cvt_kernel<<<(F_ * E_ / 4 + 255) / 256, 256, 0, stream>>>(Wqkv, Wqkvb, F_ * E_ / 4);
    cvt_kernel<<<(E_ * E_ / 4 + 255) / 256, 256, 0, stream>>>(Wo, Wob, E_ * E_ / 4);

    gemm_bt<0><<<dim3(M_ / 128, F_ / 128), 256, 0, stream>>>(Xb, Wqkvb, bqkv, QKVb, F_, E_);
    attn_kernel<<<(B_ * H_) * (T_ / 128), 512, 0, stream>>>(QKVb, Ob);
    gemm_bt<1><<<dim3(M_ / 128, E_ / 128), 256, 0, stream>>>(Ob, Wob, bo, out, E_, E_);
}